// Round 1
// baseline (974.506 us; speedup 1.0000x reference)
//
#include <hip/hip_runtime.h>
#include <cstdint>

typedef unsigned short u16;
typedef __attribute__((ext_vector_type(4))) float f32x4;
typedef __attribute__((ext_vector_type(8))) __bf16 bf16x8;
typedef __attribute__((ext_vector_type(8))) u16 u16x8;

#define C_OUT 16
#define D_IN 1024
#define HDIM 128
#define NPTS 65536
#define BN 128
#define BK 64
#define NKT (D_IN / BK)   // 16 K-tiles

__device__ __forceinline__ u16 f2bf(float f){
  uint32_t u = __builtin_bit_cast(uint32_t, f);
  u += 0x7FFFu + ((u >> 16) & 1u);   // round-to-nearest-even
  return (u16)(u >> 16);
}

__device__ __forceinline__ void gload_lds16(const void* g, void* l){
  __builtin_amdgcn_global_load_lds((const __attribute__((address_space(1))) void*)g,
                                   (__attribute__((address_space(3))) void*)l, 16, 0, 0);
}

// ---------- prep: transpose + fp32->bf16 convert ([ch][R][C] -> [ch][C][R]) ----------
__global__ __launch_bounds__(256) void transpose_cvt(const float* __restrict__ src,
                                                     u16* __restrict__ dst, int R, int C){
  __shared__ float tile[32][33];
  int ch = blockIdx.z;
  int r0 = blockIdx.y * 32, c0 = blockIdx.x * 32;
  const float* s = src + (size_t)ch * R * C;
  u16* d = dst + (size_t)ch * R * C;
  int tx = threadIdx.x, ty = threadIdx.y;
  for (int i = ty; i < 32; i += 8) tile[i][tx] = s[(size_t)(r0 + i) * C + c0 + tx];
  __syncthreads();
  for (int i = ty; i < 32; i += 8) d[(size_t)(c0 + i) * R + r0 + tx] = f2bf(tile[tx][i]);
}

// ---------- fused 3-layer MLP, bf16 MFMA, in-kernel x conversion, dbuf layer-1 ----------
// grid: blockIdx.x = ntile*16 + c  (c-minor: the 16 blocks sharing an x-tile are adjacent,
// round-robin XCD dispatch then gives each XCD only 2 channels' weights -> L2-resident)
__global__ __launch_bounds__(256, 2) void mlp_fused(const float* __restrict__ x,
    const u16* __restrict__ W1T, const u16* __restrict__ W2T,
    const float* __restrict__ b1, const float* __restrict__ b2,
    const float* __restrict__ W3, const float* __restrict__ b3,
    float* __restrict__ out){
  // double-buffered [A(128x64) | B(128x64)] bf16 = 64 KB; h1s(128x128) aliases buf0 after L1.
  __shared__ __align__(16) u16 smem[4 * BN * BK];
  __shared__ float outb[BN];

  const int t = threadIdx.x;
  const int wave = t >> 6, lane = t & 63;
  const int q = lane >> 4, s = lane & 15;
  const int wr = (wave >> 1) * 64, wc = (wave & 1) * 64;
  const int c = blockIdx.x & 15;
  const int n0 = (blockIdx.x >> 4) * BN;

  const u16* w1c = W1T + (size_t)c * HDIM * D_IN;
  const float* xblk = x + (size_t)n0 * D_IN;

  // per-thread A-staging coords: thread handles rows arow+{0,32,64,96}, 8-float chunk acol
  const int arow = t >> 3;   // 0..31
  const int acol = t & 7;    // 0..7

  f32x4 acc[4][4];
#pragma unroll
  for (int i = 0; i < 4; i++)
#pragma unroll
    for (int j = 0; j < 4; j++) acc[i][j] = (f32x4){0.f, 0.f, 0.f, 0.f};

  float4 va[4][2];   // prefetched fp32 x (4 row-groups x 8 floats = 32 VGPRs)

  auto loadA = [&](int kt){
#pragma unroll
    for (int rr = 0; rr < 4; rr++){
      const float* p = xblk + (size_t)(rr * 32 + arow) * D_IN + kt * BK + acol * 8;
      va[rr][0] = *(const float4*)p;
      va[rr][1] = *(const float4*)(p + 4);
    }
  };
  auto stageB = [&](u16* Bs, int kt){
#pragma unroll
    for (int ii = 0; ii < 4; ii++){
      int hbase = wave * 32 + ii * 8;
      int h = hbase + (lane >> 3);
      int k = kt * BK + (((lane & 7) ^ (h & 7)) * 8);   // pre-swizzled global source
      gload_lds16(w1c + (size_t)h * D_IN + k, Bs + hbase * BK);
    }
  };
  auto writeA = [&](u16* As){
#pragma unroll
    for (int rr = 0; rr < 4; rr++){
      int row = rr * 32 + arow;
      bf16x8 pv;
      pv[0] = (__bf16)va[rr][0].x; pv[1] = (__bf16)va[rr][0].y;
      pv[2] = (__bf16)va[rr][0].z; pv[3] = (__bf16)va[rr][0].w;
      pv[4] = (__bf16)va[rr][1].x; pv[5] = (__bf16)va[rr][1].y;
      pv[6] = (__bf16)va[rr][1].z; pv[7] = (__bf16)va[rr][1].w;
      *(u16x8*)&As[row * BK + ((acol ^ (row & 7)) * 8)] = __builtin_bit_cast(u16x8, pv);
    }
  };

  // ---- prologue: tile 0 into buffer 0 ----
  loadA(0);
  stageB(smem + BN * BK, 0);
  writeA(smem);
  __syncthreads();   // drains vmcnt(0): B gloads for tile 0 land here

  // ================= layer 1: [128x1024] x [1024x128], 1 barrier per K-tile =================
  for (int kt = 0; kt < NKT; kt++){
    u16* As  = smem + (kt & 1) * (2 * BN * BK);
    u16* Bs  = As + BN * BK;
    u16* Asn = smem + ((kt + 1) & 1) * (2 * BN * BK);
    u16* Bsn = Asn + BN * BK;
    if (kt < NKT - 1){
      loadA(kt + 1);        // issue HBM x-loads first (oldest in vmcnt queue)
      stageB(Bsn, kt + 1);  // weight gload_lds stays in flight across the MFMA phase
    }
#pragma unroll
    for (int ks = 0; ks < 2; ks++){
      bf16x8 a[4], b[4];
#pragma unroll
      for (int i = 0; i < 4; i++){
        int m = wr + i * 16 + s;
        int ch = ks * 4 + q;
        a[i] = __builtin_bit_cast(bf16x8, *(const u16x8*)&As[m * BK + ((ch ^ (m & 7)) * 8)]);
      }
#pragma unroll
      for (int j = 0; j < 4; j++){
        int hh = wc + j * 16 + s;
        int ch = ks * 4 + q;
        b[j] = __builtin_bit_cast(bf16x8, *(const u16x8*)&Bs[hh * BK + ((ch ^ (hh & 7)) * 8)]);
      }
#pragma unroll
      for (int i = 0; i < 4; i++)
#pragma unroll
        for (int j = 0; j < 4; j++)
          acc[i][j] = __builtin_amdgcn_mfma_f32_16x16x32_bf16(a[i], b[j], acc[i][j], 0, 0, 0);
    }
    if (kt < NKT - 1) writeA(Asn);  // waits only the x-loads (vmcnt(4)); convert + ds_write
    __syncthreads();
  }

  // ---- layer1 epilogue: bias + relu -> h1s (bf16, swizzled, aliases buf0) ----
  float b1v[4];
#pragma unroll
  for (int j = 0; j < 4; j++) b1v[j] = b1[c * HDIM + wc + j * 16 + s];
  u16* h1s = smem; // 128 x 128
#pragma unroll
  for (int i = 0; i < 4; i++)
#pragma unroll
    for (int j = 0; j < 4; j++)
#pragma unroll
      for (int r = 0; r < 4; r++){
        float v = fmaxf(acc[i][j][r] + b1v[j], 0.f);
        int m = wr + i * 16 + q * 4 + r;
        int h = wc + j * 16 + s;
        h1s[m * HDIM + (((h >> 3) ^ (m & 7)) * 8) + (h & 7)] = f2bf(v);
      }
  __syncthreads();

  // ================= layer 2: [128x128] x [128x128], B-frags direct from L2-hot W2T =================
  const u16* w2c = W2T + (size_t)c * HDIM * HDIM;
  f32x4 acc2[4][4];
#pragma unroll
  for (int i = 0; i < 4; i++)
#pragma unroll
    for (int j = 0; j < 4; j++) acc2[i][j] = (f32x4){0.f, 0.f, 0.f, 0.f};
#pragma unroll
  for (int ks = 0; ks < 4; ks++){
    bf16x8 a[4], b[4];
#pragma unroll
    for (int i = 0; i < 4; i++){
      int m = wr + i * 16 + s;
      int ch = ks * 4 + q;
      a[i] = __builtin_bit_cast(bf16x8, *(const u16x8*)&h1s[m * HDIM + ((ch ^ (m & 7)) * 8)]);
    }
#pragma unroll
    for (int j = 0; j < 4; j++){
      int col = wc + j * 16 + s;
      b[j] = __builtin_bit_cast(bf16x8, *(const u16x8*)(w2c + (size_t)col * HDIM + ks * 32 + q * 8));
    }
#pragma unroll
    for (int i = 0; i < 4; i++)
#pragma unroll
      for (int j = 0; j < 4; j++)
        acc2[i][j] = __builtin_amdgcn_mfma_f32_16x16x32_bf16(a[i], b[j], acc2[i][j], 0, 0, 0);
  }

  // ---- layer2 epilogue + layer 3 dot: shuffle-reduce across the 16-lane col group ----
  float b2v[4], w3v[4];
#pragma unroll
  for (int j = 0; j < 4; j++){
    b2v[j] = b2[c * HDIM + wc + j * 16 + s];
    w3v[j] = W3[c * HDIM + wc + j * 16 + s];
  }
  float part[4][4];
#pragma unroll
  for (int i = 0; i < 4; i++)
#pragma unroll
    for (int r = 0; r < 4; r++) part[i][r] = 0.f;
#pragma unroll
  for (int i = 0; i < 4; i++)
#pragma unroll
    for (int j = 0; j < 4; j++)
#pragma unroll
      for (int r = 0; r < 4; r++){
        float hv = fmaxf(acc2[i][j][r] + b2v[j], 0.f);
        part[i][r] = fmaf(hv, w3v[j], part[i][r]);
      }
#pragma unroll
  for (int mask = 1; mask <= 8; mask <<= 1)
#pragma unroll
    for (int i = 0; i < 4; i++)
#pragma unroll
      for (int r = 0; r < 4; r++) part[i][r] += __shfl_xor(part[i][r], mask, 64);

  if (s == 0 && wc == 0){
#pragma unroll
    for (int i = 0; i < 4; i++)
#pragma unroll
      for (int r = 0; r < 4; r++) outb[wr + i * 16 + q * 4 + r] = part[i][r];
  }
  __syncthreads();
  if (s == 0 && wc == 64){
#pragma unroll
    for (int i = 0; i < 4; i++)
#pragma unroll
      for (int r = 0; r < 4; r++) outb[wr + i * 16 + q * 4 + r] += part[i][r];
  }
  __syncthreads();
  if (t < BN) out[(size_t)(n0 + t) * C_OUT + c] = outb[t] + b3[c];
}

// ---------- slow-but-correct fallback (only if ws too small for weights) ----------
__global__ __launch_bounds__(256) void mlp_naive(const float* __restrict__ x,
    const float* __restrict__ W1, const float* __restrict__ b1,
    const float* __restrict__ W2, const float* __restrict__ b2,
    const float* __restrict__ W3, const float* __restrict__ b3,
    float* __restrict__ out){
  __shared__ float xs[16 * D_IN];
  __shared__ float h1[16 * HDIM];
  __shared__ float h2[16 * HDIM];
  int c = blockIdx.x & 15;
  int n0 = (blockIdx.x >> 4) * 16;
  int t = threadIdx.x;
  for (int i = t; i < 16 * D_IN; i += 256) xs[i] = x[(size_t)n0 * D_IN + i];
  __syncthreads();
  int h = t & 127, ng = t >> 7;
  const float* w1c = W1 + (size_t)c * D_IN * HDIM;
  float a1[8];
#pragma unroll
  for (int nn = 0; nn < 8; nn++) a1[nn] = 0.f;
  for (int d = 0; d < D_IN; d++){
    float w = w1c[(size_t)d * HDIM + h];
#pragma unroll
    for (int nn = 0; nn < 8; nn++) a1[nn] = fmaf(xs[(ng * 8 + nn) * D_IN + d], w, a1[nn]);
  }
  float bb = b1[c * HDIM + h];
#pragma unroll
  for (int nn = 0; nn < 8; nn++) h1[(ng * 8 + nn) * HDIM + h] = fmaxf(a1[nn] + bb, 0.f);
  __syncthreads();
  const float* w2c = W2 + (size_t)c * HDIM * HDIM;
  float a2[8];
#pragma unroll
  for (int nn = 0; nn < 8; nn++) a2[nn] = 0.f;
  for (int k = 0; k < HDIM; k++){
    float w = w2c[(size_t)k * HDIM + h];
#pragma unroll
    for (int nn = 0; nn < 8; nn++) a2[nn] = fmaf(h1[(ng * 8 + nn) * HDIM + k], w, a2[nn]);
  }
  bb = b2[c * HDIM + h];
#pragma unroll
  for (int nn = 0; nn < 8; nn++) h2[(ng * 8 + nn) * HDIM + h] = fmaxf(a2[nn] + bb, 0.f);
  __syncthreads();
  if (t < 16){
    float ssum = 0.f;
    for (int hh = 0; hh < HDIM; hh++) ssum = fmaf(h2[t * HDIM + hh], W3[c * HDIM + hh], ssum);
    out[(size_t)(n0 + t) * C_OUT + c] = ssum + b3[c];
  }
}

extern "C" void kernel_launch(void* const* d_in, const int* in_sizes, int n_in,
                              void* d_out, int out_size, void* d_ws, size_t ws_size,
                              hipStream_t stream){
  const float* x  = (const float*)d_in[0];
  const float* W1 = (const float*)d_in[1];
  const float* b1 = (const float*)d_in[2];
  const float* W2 = (const float*)d_in[3];
  const float* b2 = (const float*)d_in[4];
  const float* W3 = (const float*)d_in[5];
  const float* b3 = (const float*)d_in[6];
  float* out = (float*)d_out;

  const size_t W1T_elems = (size_t)C_OUT * HDIM * D_IN;   // 2,097,152
  const size_t W2T_elems = (size_t)C_OUT * HDIM * HDIM;   // 262,144
  const size_t ws_w_bytes = (W1T_elems + W2T_elems) * 2;  // 4,718,592 B

  if (ws_size < ws_w_bytes){
    mlp_naive<<<(NPTS / 16) * C_OUT, 256, 0, stream>>>(x, W1, b1, W2, b2, W3, b3, out);
    return;
  }

  u16* W1T = (u16*)d_ws;
  u16* W2T = W1T + W1T_elems;
  // W1 [c][d][h] -> W1T [c][h][d]; W2 [c][h][j] -> W2T [c][j][h]
  transpose_cvt<<<dim3(HDIM / 32, D_IN / 32, C_OUT), dim3(32, 8), 0, stream>>>(W1, W1T, D_IN, HDIM);
  transpose_cvt<<<dim3(HDIM / 32, HDIM / 32, C_OUT), dim3(32, 8), 0, stream>>>(W2, W2T, HDIM, HDIM);

  const int grid = (NPTS / BN) * C_OUT;  // 8192
  mlp_fused<<<grid, 256, 0, stream>>>(x, W1T, W2T, b1, b2, W3, b3, out);
}

// Round 2
// 870.375 us; speedup vs baseline: 1.1196x; 1.1196x over previous
//
#include <hip/hip_runtime.h>
#include <cstdint>

typedef unsigned short u16;
typedef __attribute__((ext_vector_type(4))) float f32x4;
typedef __attribute__((ext_vector_type(8))) __bf16 bf16x8;
typedef __attribute__((ext_vector_type(8))) u16 u16x8;
typedef __attribute__((ext_vector_type(4))) u16 u16x4;

#define C_OUT 16
#define D_IN 1024
#define HDIM 128
#define NPTS 65536
#define BM 256                       // x-rows per block
#define BK 64                        // K per tile
#define NKT (D_IN / BK)              // 16
#define A_ELEMS (BM * BK)            // 16384
#define B_ELEMS (HDIM * BK)          // 8192
#define BUF_ELEMS (A_ELEMS + B_ELEMS)// 24576 elems = 48 KB

__device__ __forceinline__ u16 f2bf(float f){
  uint32_t u = __builtin_bit_cast(uint32_t, f);
  u += 0x7FFFu + ((u >> 16) & 1u);   // round-to-nearest-even
  return (u16)(u >> 16);
}

__device__ __forceinline__ void gload_lds16(const void* g, void* l){
  __builtin_amdgcn_global_load_lds((const __attribute__((address_space(1))) void*)g,
                                   (__attribute__((address_space(3))) void*)l, 16, 0, 0);
}

// ---------- prep: transpose + fp32->bf16 convert ([ch][R][C] -> [ch][C][R]) ----------
__global__ __launch_bounds__(256) void transpose_cvt(const float* __restrict__ src,
                                                     u16* __restrict__ dst, int R, int C){
  __shared__ float tile[32][33];
  int ch = blockIdx.z;
  int r0 = blockIdx.y * 32, c0 = blockIdx.x * 32;
  const float* s = src + (size_t)ch * R * C;
  u16* d = dst + (size_t)ch * R * C;
  int tx = threadIdx.x, ty = threadIdx.y;
  for (int i = ty; i < 32; i += 8) tile[i][tx] = s[(size_t)(r0 + i) * C + c0 + tx];
  __syncthreads();
  for (int i = ty; i < 32; i += 8) d[(size_t)(c0 + i) * R + r0 + tx] = f2bf(tile[tx][i]);
}

__global__ __launch_bounds__(256) void cvt_x_kernel(const float4* __restrict__ src,
                                                    u16x4* __restrict__ dst, int n4){
  int stride = gridDim.x * 256;
  for (int i = blockIdx.x * 256 + threadIdx.x; i < n4; i += stride){
    float4 v = src[i];
    u16x4 o = { f2bf(v.x), f2bf(v.y), f2bf(v.z), f2bf(v.w) };
    dst[i] = o;
  }
}

// ---------- fused 3-layer MLP, bf16 MFMA ----------
// 512 threads = 8 waves (4M x 2N), BM=256 x-rows, triple-buffered K-tiles with
// counted vmcnt so prefetch loads stay in flight ACROSS raw s_barriers (T3+T4).
// grid: blockIdx.x = ntile*16 + c  (c-minor so the 16 blocks sharing an x-tile are adjacent)
__global__ __launch_bounds__(512, 2) void mlp_fused(const u16* __restrict__ xb,
    const u16* __restrict__ W1T, const u16* __restrict__ W2T,
    const float* __restrict__ b1, const float* __restrict__ b2,
    const float* __restrict__ W3, const float* __restrict__ b3,
    float* __restrict__ out){
  __shared__ __align__(16) u16 smem[3 * BUF_ELEMS];  // 144 KB (1 block/CU)
  __shared__ float outb[BM];

  const int t = threadIdx.x;
  const int wave = t >> 6, lane = t & 63;
  const int q = lane >> 4, s = lane & 15;
  const int wm = wave >> 1, wn = wave & 1;
  const int wr = wm * 64, wc = wn * 64;
  const int c = blockIdx.x & 15;
  const int n0 = (blockIdx.x >> 4) * BM;

  const u16* w1c = W1T + (size_t)c * HDIM * D_IN;

  // stage tile kt into buffer buf: 6 gload_lds per wave (4 A-chunks + 2 B-chunks).
  // LDS dest is wave-uniform + lane*16 (linear); swizzle is applied on the GLOBAL source.
  auto stage = [&](int buf, int kt){
    u16* As = smem + buf * BUF_ELEMS;
    u16* Bs = As + A_ELEMS;
#pragma unroll
    for (int ii = 0; ii < 4; ii++){
      int rbase = wave * 32 + ii * 8;
      int row = rbase + (lane >> 3);
      int k = kt * BK + (((lane & 7) ^ (row & 7)) * 8);
      gload_lds16(xb + (size_t)(n0 + row) * D_IN + k, As + rbase * BK);
    }
#pragma unroll
    for (int ii = 0; ii < 2; ii++){
      int hbase = wave * 16 + ii * 8;
      int h = hbase + (lane >> 3);
      int k = kt * BK + (((lane & 7) ^ (h & 7)) * 8);
      gload_lds16(w1c + (size_t)h * D_IN + k, Bs + hbase * BK);
    }
  };

  f32x4 acc[4][4];
#pragma unroll
  for (int i = 0; i < 4; i++)
#pragma unroll
    for (int j = 0; j < 4; j++) acc[i][j] = (f32x4){0.f, 0.f, 0.f, 0.f};

  // ---- prologue: tiles 0,1 in flight; wait tile 0 (vmcnt(6) leaves tile 1 outstanding) ----
  stage(0, 0);
  stage(1, 1);
  asm volatile("s_waitcnt vmcnt(6)" ::: "memory");
  __builtin_amdgcn_s_barrier();
  asm volatile("" ::: "memory");

  // ================= layer 1: [256x1024] x [1024x128], counted-vmcnt pipeline =================
  int cur = 0;
  for (int kt = 0; kt < NKT; kt++){
    int nx2 = cur + 2; if (nx2 >= 3) nx2 -= 3;
    if (kt + 2 < NKT) stage(nx2, kt + 2);   // issue BEFORE compute; stays in flight past barrier
    const u16* As = smem + cur * BUF_ELEMS;
    const u16* Bs = As + A_ELEMS;
#pragma unroll
    for (int ks = 0; ks < 2; ks++){
      bf16x8 a[4], b[4];
#pragma unroll
      for (int i = 0; i < 4; i++){
        int m = wr + i * 16 + s;
        int ch = ks * 4 + q;
        a[i] = __builtin_bit_cast(bf16x8, *(const u16x8*)&As[m * BK + ((ch ^ (m & 7)) * 8)]);
      }
#pragma unroll
      for (int j = 0; j < 4; j++){
        int hh = wc + j * 16 + s;
        int ch = ks * 4 + q;
        b[j] = __builtin_bit_cast(bf16x8, *(const u16x8*)&Bs[hh * BK + ((ch ^ (hh & 7)) * 8)]);
      }
#pragma unroll
      for (int i = 0; i < 4; i++)
#pragma unroll
        for (int j = 0; j < 4; j++)
          acc[i][j] = __builtin_amdgcn_mfma_f32_16x16x32_bf16(a[i], b[j], acc[i][j], 0, 0, 0);
    }
    // wait tile kt+1's loads only (kt+2's 6/wave stay outstanding); lgkmcnt(0) so this
    // buffer's ds_reads are complete before it gets overwritten / aliased after the barrier.
    if (kt + 2 < NKT) asm volatile("s_waitcnt vmcnt(6) lgkmcnt(0)" ::: "memory");
    else              asm volatile("s_waitcnt vmcnt(0) lgkmcnt(0)" ::: "memory");
    __builtin_amdgcn_s_barrier();
    asm volatile("" ::: "memory");
    cur++; if (cur == 3) cur = 0;
  }

  // ---- layer1 epilogue: bias + relu -> h1s (bf16, swizzled, aliases buffers) ----
  float b1v[4];
#pragma unroll
  for (int j = 0; j < 4; j++) b1v[j] = b1[c * HDIM + wc + j * 16 + s];
  u16* h1s = smem; // 256 x 128 bf16 = 64 KB
#pragma unroll
  for (int i = 0; i < 4; i++)
#pragma unroll
    for (int j = 0; j < 4; j++)
#pragma unroll
      for (int r = 0; r < 4; r++){
        float v = fmaxf(acc[i][j][r] + b1v[j], 0.f);
        int m = wr + i * 16 + q * 4 + r;
        int h = wc + j * 16 + s;
        h1s[m * HDIM + (((h >> 3) ^ (m & 7)) * 8) + (h & 7)] = f2bf(v);
      }
  __syncthreads();

  // ================= layer 2: [256x128] x [128x128], B-frags direct from L2-hot W2T =================
  const u16* w2c = W2T + (size_t)c * HDIM * HDIM;
  f32x4 acc2[4][4];
#pragma unroll
  for (int i = 0; i < 4; i++)
#pragma unroll
    for (int j = 0; j < 4; j++) acc2[i][j] = (f32x4){0.f, 0.f, 0.f, 0.f};
#pragma unroll
  for (int ks = 0; ks < 4; ks++){
    bf16x8 a[4], b[4];
#pragma unroll
    for (int i = 0; i < 4; i++){
      int m = wr + i * 16 + s;
      int ch = ks * 4 + q;
      a[i] = __builtin_bit_cast(bf16x8, *(const u16x8*)&h1s[m * HDIM + ((ch ^ (m & 7)) * 8)]);
    }
#pragma unroll
    for (int j = 0; j < 4; j++){
      int col = wc + j * 16 + s;
      b[j] = __builtin_bit_cast(bf16x8, *(const u16x8*)(w2c + (size_t)col * HDIM + ks * 32 + q * 8));
    }
#pragma unroll
    for (int i = 0; i < 4; i++)
#pragma unroll
      for (int j = 0; j < 4; j++)
        acc2[i][j] = __builtin_amdgcn_mfma_f32_16x16x32_bf16(a[i], b[j], acc2[i][j], 0, 0, 0);
  }

  // ---- layer2 epilogue + layer 3 dot: shuffle-reduce across the 16-lane col group ----
  float b2v[4], w3v[4];
#pragma unroll
  for (int j = 0; j < 4; j++){
    b2v[j] = b2[c * HDIM + wc + j * 16 + s];
    w3v[j] = W3[c * HDIM + wc + j * 16 + s];
  }
  float part[4][4];
#pragma unroll
  for (int i = 0; i < 4; i++)
#pragma unroll
    for (int r = 0; r < 4; r++) part[i][r] = 0.f;
#pragma unroll
  for (int i = 0; i < 4; i++)
#pragma unroll
    for (int j = 0; j < 4; j++)
#pragma unroll
      for (int r = 0; r < 4; r++){
        float hv = fmaxf(acc2[i][j][r] + b2v[j], 0.f);
        part[i][r] = fmaf(hv, w3v[j], part[i][r]);
      }
#pragma unroll
  for (int mask = 1; mask <= 8; mask <<= 1)
#pragma unroll
    for (int i = 0; i < 4; i++)
#pragma unroll
      for (int r = 0; r < 4; r++) part[i][r] += __shfl_xor(part[i][r], mask, 64);

  if (s == 0 && wn == 0){
#pragma unroll
    for (int i = 0; i < 4; i++)
#pragma unroll
      for (int r = 0; r < 4; r++) outb[wr + i * 16 + q * 4 + r] = part[i][r];
  }
  __syncthreads();
  if (s == 0 && wn == 1){
#pragma unroll
    for (int i = 0; i < 4; i++)
#pragma unroll
      for (int r = 0; r < 4; r++) outb[wr + i * 16 + q * 4 + r] += part[i][r];
  }
  __syncthreads();
  if (t < BM) out[(size_t)(n0 + t) * C_OUT + c] = outb[t] + b3[c];
}

// ---------- slow-but-correct fallback (only if ws too small) ----------
__global__ __launch_bounds__(256) void mlp_naive(const float* __restrict__ x,
    const float* __restrict__ W1, const float* __restrict__ b1,
    const float* __restrict__ W2, const float* __restrict__ b2,
    const float* __restrict__ W3, const float* __restrict__ b3,
    float* __restrict__ out){
  __shared__ float xs[16 * D_IN];
  __shared__ float h1[16 * HDIM];
  __shared__ float h2[16 * HDIM];
  int c = blockIdx.x & 15;
  int n0 = (blockIdx.x >> 4) * 16;
  int t = threadIdx.x;
  for (int i = t; i < 16 * D_IN; i += 256) xs[i] = x[(size_t)n0 * D_IN + i];
  __syncthreads();
  int h = t & 127, ng = t >> 7;
  const float* w1c = W1 + (size_t)c * D_IN * HDIM;
  float a1[8];
#pragma unroll
  for (int nn = 0; nn < 8; nn++) a1[nn] = 0.f;
  for (int d = 0; d < D_IN; d++){
    float w = w1c[(size_t)d * HDIM + h];
#pragma unroll
    for (int nn = 0; nn < 8; nn++) a1[nn] = fmaf(xs[(ng * 8 + nn) * D_IN + d], w, a1[nn]);
  }
  float bb = b1[c * HDIM + h];
#pragma unroll
  for (int nn = 0; nn < 8; nn++) h1[(ng * 8 + nn) * HDIM + h] = fmaxf(a1[nn] + bb, 0.f);
  __syncthreads();
  const float* w2c = W2 + (size_t)c * HDIM * HDIM;
  float a2[8];
#pragma unroll
  for (int nn = 0; nn < 8; nn++) a2[nn] = 0.f;
  for (int k = 0; k < HDIM; k++){
    float w = w2c[(size_t)k * HDIM + h];
#pragma unroll
    for (int nn = 0; nn < 8; nn++) a2[nn] = fmaf(h1[(ng * 8 + nn) * HDIM + k], w, a2[nn]);
  }
  bb = b2[c * HDIM + h];
#pragma unroll
  for (int nn = 0; nn < 8; nn++) h2[(ng * 8 + nn) * HDIM + h] = fmaxf(a2[nn] + bb, 0.f);
  __syncthreads();
  if (t < 16){
    float ssum = 0.f;
    for (int hh = 0; hh < HDIM; hh++) ssum = fmaf(h2[t * HDIM + hh], W3[c * HDIM + hh], ssum);
    out[(size_t)(n0 + t) * C_OUT + c] = ssum + b3[c];
  }
}

extern "C" void kernel_launch(void* const* d_in, const int* in_sizes, int n_in,
                              void* d_out, int out_size, void* d_ws, size_t ws_size,
                              hipStream_t stream){
  const float* x  = (const float*)d_in[0];
  const float* W1 = (const float*)d_in[1];
  const float* b1 = (const float*)d_in[2];
  const float* W2 = (const float*)d_in[3];
  const float* b2 = (const float*)d_in[4];
  const float* W3 = (const float*)d_in[5];
  const float* b3 = (const float*)d_in[6];
  float* out = (float*)d_out;

  const size_t W1T_elems = (size_t)C_OUT * HDIM * D_IN;   // 2,097,152
  const size_t W2T_elems = (size_t)C_OUT * HDIM * HDIM;   // 262,144
  const size_t ws_w_bytes = (W1T_elems + W2T_elems) * 2;  // 4,718,592 B
  const size_t xb_bytes   = (size_t)NPTS * D_IN * 2;      // 134,217,728 B

  if (ws_size < ws_w_bytes + xb_bytes){
    mlp_naive<<<(NPTS / 16) * C_OUT, 256, 0, stream>>>(x, W1, b1, W2, b2, W3, b3, out);
    return;
  }

  u16* W1T = (u16*)d_ws;
  u16* W2T = W1T + W1T_elems;
  u16* xb  = W2T + W2T_elems;
  // W1 [c][d][h] -> W1T [c][h][d]; W2 [c][h][j] -> W2T [c][j][h]
  transpose_cvt<<<dim3(HDIM / 32, D_IN / 32, C_OUT), dim3(32, 8), 0, stream>>>(W1, W1T, D_IN, HDIM);
  transpose_cvt<<<dim3(HDIM / 32, HDIM / 32, C_OUT), dim3(32, 8), 0, stream>>>(W2, W2T, HDIM, HDIM);
  cvt_x_kernel<<<8192, 256, 0, stream>>>((const float4*)x, (u16x4*)xb, NPTS * D_IN / 4);

  const int grid = (NPTS / BM) * C_OUT;  // 4096 blocks of 512 threads
  mlp_fused<<<grid, 512, 0, stream>>>(xb, W1T, W2T, b1, b2, W3, b3, out);
}

// Round 3
// 732.780 us; speedup vs baseline: 1.3299x; 1.1878x over previous
//
#include <hip/hip_runtime.h>
#include <cstdint>

typedef unsigned short u16;
typedef __attribute__((ext_vector_type(4))) float f32x4;
typedef __attribute__((ext_vector_type(8))) __bf16 bf16x8;
typedef __attribute__((ext_vector_type(8))) u16 u16x8;
typedef __attribute__((ext_vector_type(4))) u16 u16x4;

#define C_OUT 16
#define D_IN 1024
#define HDIM 128
#define NPTS 65536
#define BM 256                        // x-rows per block
#define BN 256                        // 2 channels x 128 h
#define BK 64
#define NKT (D_IN / BK)               // 16
#define BUF_U16 (2 * BM * BK)         // A(256x64) + B(256x64) = 32768 u16 = 64 KB per buffer

__device__ __forceinline__ u16 f2bf(float f){
  uint32_t u = __builtin_bit_cast(uint32_t, f);
  u += 0x7FFFu + ((u >> 16) & 1u);   // round-to-nearest-even
  return (u16)(u >> 16);
}

__device__ __forceinline__ void gload_lds16(const void* g, void* l){
  __builtin_amdgcn_global_load_lds((const __attribute__((address_space(1))) void*)g,
                                   (__attribute__((address_space(3))) void*)l, 16, 0, 0);
}

// ---------- prep: transpose + fp32->bf16 convert ([ch][R][C] -> [ch][C][R]) ----------
__global__ __launch_bounds__(256) void transpose_cvt(const float* __restrict__ src,
                                                     u16* __restrict__ dst, int R, int C){
  __shared__ float tile[32][33];
  int ch = blockIdx.z;
  int r0 = blockIdx.y * 32, c0 = blockIdx.x * 32;
  const float* s = src + (size_t)ch * R * C;
  u16* d = dst + (size_t)ch * R * C;
  int tx = threadIdx.x, ty = threadIdx.y;
  for (int i = ty; i < 32; i += 8) tile[i][tx] = s[(size_t)(r0 + i) * C + c0 + tx];
  __syncthreads();
  for (int i = ty; i < 32; i += 8) d[(size_t)(c0 + i) * R + r0 + tx] = f2bf(tile[tx][i]);
}

__global__ __launch_bounds__(256) void cvt_x_kernel(const float4* __restrict__ src,
                                                    u16x4* __restrict__ dst, int n4){
  int stride = gridDim.x * 256;
  for (int i = blockIdx.x * 256 + threadIdx.x; i < n4; i += stride){
    float4 v = src[i];
    u16x4 o = { f2bf(v.x), f2bf(v.y), f2bf(v.z), f2bf(v.w) };
    dst[i] = o;
  }
}

// ---------- fused 3-layer MLP: m201-style 8-phase schedule, channel-paired BN=256 ----------
// 512 thr = 8 waves (2M x 4N); wave tile 128x64. LDS: 2-buf ring (128 KB) -> h1s alias.
// Per K-tile: 4 fine phases {ds_read frags | stage 2x4 gloads (phases 0-1) | barrier |
// lgkmcnt(0) | setprio(1) 16 MFMA setprio(0) | barrier}; vmcnt(0) only at phase 3.
// grid: blockIdx.x = mtile*8 + cp (cp-minor: blocks sharing an x-tile are adjacent).
__global__ __launch_bounds__(512, 2) void mlp_fused(const u16* __restrict__ xb,
    const u16* __restrict__ W1T, const u16* __restrict__ W2T,
    const float* __restrict__ b1, const float* __restrict__ b2,
    const float* __restrict__ W3, const float* __restrict__ b3,
    float* __restrict__ out){
  __shared__ __align__(16) u16 smem[2 * BUF_U16];   // 128 KB ring; h1s[256][256] aliases it
  __shared__ float outb[2][BM];

  const int t = threadIdx.x;
  const int wave = t >> 6, lane = t & 63;
  const int q = lane >> 4, s = lane & 15;
  const int wm = wave >> 2, wn = wave & 3;     // 2M x 4N wave grid
  const int wr = wm * 128, wc = wn * 64;
  const int cp = blockIdx.x & 7;
  const int c0 = cp * 2;
  const int n0 = (blockIdx.x >> 3) * BM;

  const u16* w1a = W1T + (size_t)c0 * HDIM * D_IN;        // B rows   0..127 (channel c0)
  const u16* w1b = W1T + (size_t)(c0 + 1) * HDIM * D_IN;  // B rows 128..255 (channel c0+1)
  const int l8 = lane >> 3, l7 = lane & 7;

  // wave w stages A rows [w*32,+32) and B rows [w*32,+32); gload j covers 8 rows.
  // LDS dest linear (wave-uniform base + lane*16); XOR swizzle applied on GLOBAL source.
  auto stageA = [&](u16* Ab, int kt, int j){
    int rbase = wave * 32 + j * 8;
    int row = rbase + l8;
    int k = kt * BK + ((l7 ^ (row & 7)) * 8);
    gload_lds16(xb + (size_t)(n0 + row) * D_IN + k, Ab + rbase * BK);
  };
  auto stageB = [&](u16* Bb, int kt, int j){
    int rbase = wave * 32 + j * 8;
    const u16* srcb = (rbase < 128) ? (w1a + (size_t)rbase * D_IN)
                                    : (w1b + (size_t)(rbase - 128) * D_IN);
    int row = rbase + l8;
    int k = kt * BK + ((l7 ^ (row & 7)) * 8);
    gload_lds16(srcb + (size_t)l8 * D_IN + k, Bb + rbase * BK);
  };

  f32x4 acc[8][4];
#pragma unroll
  for (int i = 0; i < 8; i++)
#pragma unroll
    for (int j = 0; j < 4; j++) acc[i][j] = (f32x4){0.f, 0.f, 0.f, 0.f};

  // ---- prologue: tile 0 -> buf0 ----
#pragma unroll
  for (int j = 0; j < 4; j++) stageA(smem, 0, j);
#pragma unroll
  for (int j = 0; j < 4; j++) stageB(smem + BM * BK, 0, j);
  asm volatile("s_waitcnt vmcnt(0)" ::: "memory");
  __builtin_amdgcn_s_barrier();

  // ================= layer 1: [256x1024] x [1024x256], 4 fine phases per K-tile =================
  for (int kt = 0; kt < NKT; kt++){
    u16* Ab = smem + (kt & 1) * BUF_U16;
    u16* Bb = Ab + BM * BK;
    u16* An = smem + ((kt + 1) & 1) * BUF_U16;
    u16* Bn = An + BM * BK;
    bf16x8 bfr[4][2];                      // B frags: read once (phase 0), live all 4 phases
#pragma unroll
    for (int qd = 0; qd < 4; qd++){        // phase = one C-quadrant (2 m-frags) x K=64
      bf16x8 afr[2][2];
#pragma unroll
      for (int mf2 = 0; mf2 < 2; mf2++)
#pragma unroll
        for (int ks = 0; ks < 2; ks++){
          int m = wr + (qd * 2 + mf2) * 16 + s;
          int ch = ks * 4 + q;
          afr[mf2][ks] = __builtin_bit_cast(bf16x8,
              *(const u16x8*)&Ab[m * BK + ((ch ^ (m & 7)) * 8)]);
        }
      if (qd == 0){
#pragma unroll
        for (int nf = 0; nf < 4; nf++)
#pragma unroll
          for (int ks = 0; ks < 2; ks++){
            int h = wc + nf * 16 + s;
            int ch = ks * 4 + q;
            bfr[nf][ks] = __builtin_bit_cast(bf16x8,
                *(const u16x8*)&Bb[h * BK + ((ch ^ (h & 7)) * 8)]);
          }
      }
      if (qd < 2 && kt + 1 < NKT){         // front-loaded stage: 4 gloads in each of phases 0,1
        stageA(An, kt + 1, qd * 2); stageA(An, kt + 1, qd * 2 + 1);
        stageB(Bn, kt + 1, qd * 2); stageB(Bn, kt + 1, qd * 2 + 1);
      }
      __builtin_amdgcn_s_barrier();
      asm volatile("s_waitcnt lgkmcnt(0)" ::: "memory");
      __builtin_amdgcn_s_setprio(1);
#pragma unroll
      for (int ks = 0; ks < 2; ks++)
#pragma unroll
        for (int mf2 = 0; mf2 < 2; mf2++)
#pragma unroll
          for (int nf = 0; nf < 4; nf++)
            acc[qd * 2 + mf2][nf] = __builtin_amdgcn_mfma_f32_16x16x32_bf16(
                afr[mf2][ks], bfr[nf][ks], acc[qd * 2 + mf2][nf], 0, 0, 0);
      __builtin_amdgcn_s_setprio(0);
      if (qd == 3) asm volatile("s_waitcnt vmcnt(0)" ::: "memory");  // next tile staged & landed
      __builtin_amdgcn_s_barrier();
    }
  }

  // ---- layer1 epilogue: bias + relu -> h1s[256][256] bf16 swizzled (aliases ring) ----
  const int ch1 = wn >> 1;                 // this wave's channel (0/1) for layers 2/3
  const int cwc = (wn & 1) * 64;           // within-channel col base
  float b1v[4];
#pragma unroll
  for (int nf = 0; nf < 4; nf++) b1v[nf] = b1[(c0 + ch1) * HDIM + cwc + nf * 16 + s];
  u16* h1s = smem;
#pragma unroll
  for (int mf = 0; mf < 8; mf++)
#pragma unroll
    for (int nf = 0; nf < 4; nf++)
#pragma unroll
      for (int r = 0; r < 4; r++){
        float v = fmaxf(acc[mf][nf][r] + b1v[nf], 0.f);
        int m = wr + mf * 16 + q * 4 + r;
        int colg = wc + nf * 16 + s;       // global col 0..255
        h1s[m * BN + (((colg >> 3) ^ (m & 7)) * 8) + (colg & 7)] = f2bf(v);
      }
  __syncthreads();

  // ================= layer 2: per channel [256x128] x [128x128], B direct from L2-hot W2T =================
  const u16* w2c = W2T + (size_t)(c0 + ch1) * HDIM * HDIM;
  f32x4 acc2[8][4];
#pragma unroll
  for (int i = 0; i < 8; i++)
#pragma unroll
    for (int j = 0; j < 4; j++) acc2[i][j] = (f32x4){0.f, 0.f, 0.f, 0.f};
#pragma unroll
  for (int ks = 0; ks < 4; ks++){
    bf16x8 a2[8], b2f[4];
#pragma unroll
    for (int mf = 0; mf < 8; mf++){
      int m = wr + mf * 16 + s;
      int chg = ch1 * 16 + ks * 4 + q;     // global col-chunk of this channel's k-range
      a2[mf] = __builtin_bit_cast(bf16x8,
          *(const u16x8*)&h1s[m * BN + ((chg ^ (m & 7)) * 8)]);
    }
#pragma unroll
    for (int nf = 0; nf < 4; nf++){
      int col = cwc + nf * 16 + s;
      b2f[nf] = __builtin_bit_cast(bf16x8,
          *(const u16x8*)(w2c + (size_t)col * HDIM + ks * 32 + q * 8));
    }
#pragma unroll
    for (int mf = 0; mf < 8; mf++)
#pragma unroll
      for (int nf = 0; nf < 4; nf++)
        acc2[mf][nf] = __builtin_amdgcn_mfma_f32_16x16x32_bf16(a2[mf], b2f[nf], acc2[mf][nf], 0, 0, 0);
  }

  // ---- layer2 epilogue + layer 3 dot: shuffle-reduce across the 16-lane col group ----
  float b2v[4], w3v[4];
#pragma unroll
  for (int nf = 0; nf < 4; nf++){
    b2v[nf] = b2[(c0 + ch1) * HDIM + cwc + nf * 16 + s];
    w3v[nf] = W3[(c0 + ch1) * HDIM + cwc + nf * 16 + s];
  }
  float part[8][4];
#pragma unroll
  for (int mf = 0; mf < 8; mf++)
#pragma unroll
    for (int r = 0; r < 4; r++) part[mf][r] = 0.f;
#pragma unroll
  for (int mf = 0; mf < 8; mf++)
#pragma unroll
    for (int nf = 0; nf < 4; nf++)
#pragma unroll
      for (int r = 0; r < 4; r++){
        float hv = fmaxf(acc2[mf][nf][r] + b2v[nf], 0.f);
        part[mf][r] = fmaf(hv, w3v[nf], part[mf][r]);
      }
#pragma unroll
  for (int mask = 1; mask <= 8; mask <<= 1)
#pragma unroll
    for (int mf = 0; mf < 8; mf++)
#pragma unroll
      for (int r = 0; r < 4; r++) part[mf][r] += __shfl_xor(part[mf][r], mask, 64);

  if (s == 0 && (wn & 1) == 0){            // wn 0 -> c0, wn 2 -> c1
#pragma unroll
    for (int mf = 0; mf < 8; mf++)
#pragma unroll
      for (int r = 0; r < 4; r++) outb[ch1][wr + mf * 16 + q * 4 + r] = part[mf][r];
  }
  __syncthreads();
  if (s == 0 && (wn & 1) == 1){            // wn 1 -> c0, wn 3 -> c1
#pragma unroll
    for (int mf = 0; mf < 8; mf++)
#pragma unroll
      for (int r = 0; r < 4; r++) outb[ch1][wr + mf * 16 + q * 4 + r] += part[mf][r];
  }
  __syncthreads();
  {
    int chn = t >> 8, row = t & 255;       // 512 threads cover 2 x 256 outputs
    out[(size_t)(n0 + row) * C_OUT + c0 + chn] = outb[chn][row] + b3[c0 + chn];
  }
}

// ---------- slow-but-correct fallback (only if ws too small) ----------
__global__ __launch_bounds__(256) void mlp_naive(const float* __restrict__ x,
    const float* __restrict__ W1, const float* __restrict__ b1,
    const float* __restrict__ W2, const float* __restrict__ b2,
    const float* __restrict__ W3, const float* __restrict__ b3,
    float* __restrict__ out){
  __shared__ float xs[16 * D_IN];
  __shared__ float h1[16 * HDIM];
  __shared__ float h2[16 * HDIM];
  int c = blockIdx.x & 15;
  int n0 = (blockIdx.x >> 4) * 16;
  int t = threadIdx.x;
  for (int i = t; i < 16 * D_IN; i += 256) xs[i] = x[(size_t)n0 * D_IN + i];
  __syncthreads();
  int h = t & 127, ng = t >> 7;
  const float* w1c = W1 + (size_t)c * D_IN * HDIM;
  float a1[8];
#pragma unroll
  for (int nn = 0; nn < 8; nn++) a1[nn] = 0.f;
  for (int d = 0; d < D_IN; d++){
    float w = w1c[(size_t)d * HDIM + h];
#pragma unroll
    for (int nn = 0; nn < 8; nn++) a1[nn] = fmaf(xs[(ng * 8 + nn) * D_IN + d], w, a1[nn]);
  }
  float bb = b1[c * HDIM + h];
#pragma unroll
  for (int nn = 0; nn < 8; nn++) h1[(ng * 8 + nn) * HDIM + h] = fmaxf(a1[nn] + bb, 0.f);
  __syncthreads();
  const float* w2c = W2 + (size_t)c * HDIM * HDIM;
  float a2[8];
#pragma unroll
  for (int nn = 0; nn < 8; nn++) a2[nn] = 0.f;
  for (int k = 0; k < HDIM; k++){
    float w = w2c[(size_t)k * HDIM + h];
#pragma unroll
    for (int nn = 0; nn < 8; nn++) a2[nn] = fmaf(h1[(ng * 8 + nn) * HDIM + k], w, a2[nn]);
  }
  bb = b2[c * HDIM + h];
#pragma unroll
  for (int nn = 0; nn < 8; nn++) h2[(ng * 8 + nn) * HDIM + h] = fmaxf(a2[nn] + bb, 0.f);
  __syncthreads();
  if (t < 16){
    float ssum = 0.f;
    for (int hh = 0; hh < HDIM; hh++) ssum = fmaf(h2[t * HDIM + hh], W3[c * HDIM + hh], ssum);
    out[(size_t)(n0 + t) * C_OUT + c] = ssum + b3[c];
  }
}

extern "C" void kernel_launch(void* const* d_in, const int* in_sizes, int n_in,
                              void* d_out, int out_size, void* d_ws, size_t ws_size,
                              hipStream_t stream){
  const float* x  = (const float*)d_in[0];
  const float* W1 = (const float*)d_in[1];
  const float* b1 = (const float*)d_in[2];
  const float* W2 = (const float*)d_in[3];
  const float* b2 = (const float*)d_in[4];
  const float* W3 = (const float*)d_in[5];
  const float* b3 = (const float*)d_in[6];
  float* out = (float*)d_out;

  const size_t W1T_elems = (size_t)C_OUT * HDIM * D_IN;   // 2,097,152
  const size_t W2T_elems = (size_t)C_OUT * HDIM * HDIM;   // 262,144
  const size_t ws_w_bytes = (W1T_elems + W2T_elems) * 2;  // 4,718,592 B
  const size_t xb_bytes   = (size_t)NPTS * D_IN * 2;      // 134,217,728 B

  if (ws_size < ws_w_bytes + xb_bytes){
    mlp_naive<<<(NPTS / 16) * C_OUT, 256, 0, stream>>>(x, W1, b1, W2, b2, W3, b3, out);
    return;
  }

  u16* W1T = (u16*)d_ws;
  u16* W2T = W1T + W1T_elems;
  u16* xb  = W2T + W2T_elems;
  // W1 [c][d][h] -> W1T [c][h][d]; W2 [c][h][j] -> W2T [c][j][h]
  transpose_cvt<<<dim3(HDIM / 32, D_IN / 32, C_OUT), dim3(32, 8), 0, stream>>>(W1, W1T, D_IN, HDIM);
  transpose_cvt<<<dim3(HDIM / 32, HDIM / 32, C_OUT), dim3(32, 8), 0, stream>>>(W2, W2T, HDIM, HDIM);
  cvt_x_kernel<<<8192, 256, 0, stream>>>((const float4*)x, (u16x4*)xb, NPTS * D_IN / 4);

  const int grid = (NPTS / BM) * (C_OUT / 2);  // 2048 blocks of 512 threads
  mlp_fused<<<grid, 512, 0, stream>>>(xb, W1T, W2T, b1, b2, W3, b3, out);
}